// Round 11
// baseline (496.471 us; speedup 1.0000x reference)
//
#include <hip/hip_runtime.h>
#include <hip/hip_bf16.h>

// ---------------------------------------------------------------------------
// Bidirectional Mamba block on MI355X (gfx950).  R11.
// R10 = 456 us. Profile shows harness 256 MiB ws-poison fills at 40 us as the
// top dispatches => ws_size = 256 MiB; our kernels are all < 40 us and time
// is spread across ~25 launches with per-direction duplication.
// R11: FUSE both directions into single launches (10 dispatches total):
//   cvt_all -> make_atab_both -> gemm1 -> conv_both -> gemm3(z=2) ->
//   gemm4(z=2) -> pass1_both -> pass2_both -> fixup_both -> gemm2.
// Fused fixup computes fwd+rev and writes yb ONCE (no rev read-modify-write;
// silu(z) shared).  ws plan 208.7 MiB <= 256 MiB, no aliasing.
// ---------------------------------------------------------------------------

using bf16h = __hip_bfloat16;
typedef __bf16 bf16x8 __attribute__((ext_vector_type(8)));
typedef __bf16 bf16x4 __attribute__((ext_vector_type(4)));
typedef __bf16 bf16x2 __attribute__((ext_vector_type(2)));
typedef float f32x4 __attribute__((ext_vector_type(4)));
typedef float f32x2 __attribute__((ext_vector_type(2)));

#define BB 4
#define LL 2048
#define DM 512
#define DI 1024
#define DS 16
#define MR (BB * LL)   // 8192 rows
#define NC 64          // scan chunks
#define LC 32          // chunk length
#define LOG2E 1.44269504088896f

#if defined(__has_builtin)
#if __has_builtin(__builtin_amdgcn_exp2f)
#define EXP2F(x) __builtin_amdgcn_exp2f(x)
#else
#define EXP2F(x) exp2f(x)
#endif
#else
#define EXP2F(x) exp2f(x)
#endif

// async global->LDS, 16B per lane; LDS dest is wave-uniform base (+lane*16 by HW)
__device__ __forceinline__ void async_copy16(const void* g, void* l) {
    __builtin_amdgcn_global_load_lds(
        (const __attribute__((address_space(1))) unsigned int*)g,
        (__attribute__((address_space(3))) unsigned int*)l,
        16, 0, 0);
}

// One kernel converts all 7 f32 tensors to bf16. Segment block counts
// (256 threads x 4 elems = 1024 elems/block):
//   hidden 4M->4096 | W_in 1M->1024 | Wx_f 64K->64 | Wx_r 64K->64 |
//   Wdt_f 32K->32 | Wdt_r 32K->32 | W_out 512K->512   (grid 5824)
__global__ __launch_bounds__(256) void cvt_all(
    const float* __restrict__ s0, const float* __restrict__ s1,
    const float* __restrict__ s2, const float* __restrict__ s3,
    const float* __restrict__ s4, const float* __restrict__ s5,
    const float* __restrict__ s6,
    bf16h* __restrict__ d0, bf16h* __restrict__ d1, bf16h* __restrict__ d2,
    bf16h* __restrict__ d3, bf16h* __restrict__ d4, bf16h* __restrict__ d5,
    bf16h* __restrict__ d6)
{
    int blk = blockIdx.x;
    const float* src; bf16h* dst; int off;
    if      (blk < 4096) { src = s0; dst = d0; off = blk; }
    else if (blk < 5120) { src = s1; dst = d1; off = blk - 4096; }
    else if (blk < 5184) { src = s2; dst = d2; off = blk - 5120; }
    else if (blk < 5248) { src = s3; dst = d3; off = blk - 5184; }
    else if (blk < 5280) { src = s4; dst = d4; off = blk - 5248; }
    else if (blk < 5312) { src = s5; dst = d5; off = blk - 5280; }
    else                 { src = s6; dst = d6; off = blk - 5312; }
    int i = off * 256 + threadIdx.x;
    f32x4 v = ((const f32x4*)src)[i];
    bf16x4 o;
#pragma unroll
    for (int j = 0; j < 4; ++j) o[j] = (__bf16)v[j];
    ((bf16x4*)dst)[i] = o;
}

// Atab[n*DI + d] = -exp(Alog[d*DS + n]) * log2(e), both directions.
__global__ __launch_bounds__(256) void make_atab_both(
    const float* __restrict__ Al_f, const float* __restrict__ Al_r,
    float* __restrict__ At_f, float* __restrict__ At_r)
{
    int i = blockIdx.x * 256 + threadIdx.x;     // over 2*DS*DI
    int dir = i >> 14, j = i & (DS * DI - 1);
    int d = j & (DI - 1), n = j >> 10;
    const float* Al = dir ? Al_r : Al_f;
    float* At = dir ? At_r : At_f;
    At[j] = -__expf(Al[d * DS + n]) * LOG2E;
}

// NT GEMM: C[m][n] = sum_k A[m][k] * B[n][k]; A,B bf16 row-major.
// blockIdx.z selects pointer set (A2/B2/O2/bias2) for dual-direction launches.
// EPI: 0 = bf16 store O | 1 = f32 store OF1 |
//      2 = split: col<1024 -> O1, col>=1024 -> O2 (both ld 1024; z==0 only) |
//      3 = softplus(acc + bias[col]) -> bf16 O.
template <int BM, int BN, int BK, int WROWS, int WCOLS, int EPI>
__global__ __launch_bounds__(256) void gemm_nt(
    const __bf16* __restrict__ A1, const __bf16* __restrict__ B1,
    const __bf16* __restrict__ A2, const __bf16* __restrict__ B2,
    float* __restrict__ OF1, bf16h* O1, bf16h* O2,
    const float* bias1, const float* bias2,
    int K, int lda, int ldb, int ldc)
{
    constexpr int MT  = BM / (16 * WROWS);
    constexpr int NT_ = BN / (16 * WCOLS);
    constexpr int KCH = BK / 8;             // 16B chunks per row
    constexpr int ACH = BM * KCH / 256;
    constexpr int BCH = BN * KCH / 256;
    __shared__ alignas(16) __bf16 As[BM * BK];
    __shared__ alignas(16) __bf16 Bs[BN * BK];

    const __bf16* A = A1; const __bf16* B = B1;
    bf16h* OB = O1; const float* bias = bias1;
    if (blockIdx.z) { A = A2; B = B2; OB = O2; bias = bias2; }

    const int tid  = threadIdx.x, wave = tid >> 6, lane = tid & 63;
    const int quad = lane >> 4, l16 = lane & 15;
    const int wm = wave / WCOLS, wn = wave % WCOLS;
    const int bm0 = blockIdx.y * BM, bn0 = blockIdx.x * BN;

    f32x4 acc[MT][NT_];
#pragma unroll
    for (int i = 0; i < MT; ++i)
#pragma unroll
        for (int j = 0; j < NT_; ++j) acc[i][j] = (f32x4){0.f, 0.f, 0.f, 0.f};

    for (int k0 = 0; k0 < K; k0 += BK) {
#pragma unroll
        for (int i = 0; i < ACH; ++i) {
            int c = i * 256 + wave * 64 + lane;
            int r = c / KCH, cb = c % KCH;
            async_copy16(A + (size_t)(bm0 + r) * lda + k0 + cb * 8,
                         (void*)(As + (size_t)(i * 256 + wave * 64) * 8));
        }
#pragma unroll
        for (int i = 0; i < BCH; ++i) {
            int c = i * 256 + wave * 64 + lane;
            int r = c / KCH, cb = c % KCH;
            async_copy16(B + (size_t)(bn0 + r) * ldb + k0 + cb * 8,
                         (void*)(Bs + (size_t)(i * 256 + wave * 64) * 8));
        }
        __syncthreads();
#pragma unroll
        for (int kk = 0; kk < BK; kk += 32) {
            bf16x8 af[MT], bfv[NT_];
#pragma unroll
            for (int i = 0; i < MT; ++i)
                af[i] = *(const bf16x8*)&As[(wm * MT * 16 + i * 16 + l16) * BK + kk + quad * 8];
#pragma unroll
            for (int j = 0; j < NT_; ++j)
                bfv[j] = *(const bf16x8*)&Bs[(wn * NT_ * 16 + j * 16 + l16) * BK + kk + quad * 8];
#pragma unroll
            for (int i = 0; i < MT; ++i)
#pragma unroll
                for (int j = 0; j < NT_; ++j)
                    acc[i][j] = __builtin_amdgcn_mfma_f32_16x16x32_bf16(af[i], bfv[j], acc[i][j], 0, 0, 0);
        }
        __syncthreads();
    }

#pragma unroll
    for (int i = 0; i < MT; ++i)
#pragma unroll
        for (int j = 0; j < NT_; ++j) {
            int row0 = bm0 + wm * MT * 16 + i * 16 + quad * 4;  // C/D: row = quad*4+reg
            int col  = bn0 + wn * NT_ * 16 + j * 16 + l16;      // C/D: col = lane&15
#pragma unroll
            for (int r = 0; r < 4; ++r) {
                float v = acc[i][j][r];
                int row = row0 + r;
                if constexpr (EPI == 0) {
                    OB[(size_t)row * ldc + col] = __float2bfloat16(v);
                } else if constexpr (EPI == 1) {
                    OF1[(size_t)row * ldc + col] = v;
                } else if constexpr (EPI == 2) {
                    if (col < 1024) O1[(size_t)row * 1024 + col] = __float2bfloat16(v);
                    else O2[(size_t)row * 1024 + (col - 1024)] = __float2bfloat16(v);
                } else {
                    v += bias[col];
                    float sp = (v > 20.f) ? v : log1pf(__expf(v));
                    OB[(size_t)row * ldc + col] = __float2bfloat16(sp);
                }
            }
        }
}

// Both-direction depthwise conv + silu, 8 d/thread; x loaded once.
// fwd: a += wf[k]*x[t-3+k]; rev: a += wr[k]*x[t+3-k]  (j7 = t offset + 3).
__global__ __launch_bounds__(256) void conv_both(
    const bf16h* __restrict__ xp,
    const float* __restrict__ wf, const float* __restrict__ bf_,
    const float* __restrict__ wr, const float* __restrict__ br_,
    bf16h* __restrict__ xf, bf16h* __restrict__ xr)
{
    int idx = blockIdx.x * 256 + threadIdx.x;   // over MR*DI/8
    int d0 = (idx << 3) & (DI - 1);
    size_t row = (size_t)(idx >> 7);            // 128 threads per row
    int t = (int)(row & (LL - 1));
    int b = (int)(row >> 11);

    f32x4 wvf[8], wvr[8];
#pragma unroll
    for (int j = 0; j < 8; ++j) {
        wvf[j] = ((const f32x4*)(wf + (size_t)d0 * 4))[j];
        wvr[j] = ((const f32x4*)(wr + (size_t)d0 * 4))[j];
    }
    float af[8], ar[8];
#pragma unroll
    for (int j = 0; j < 4; ++j) {
        f32x4 b0 = ((const f32x4*)(bf_ + d0))[j >> 2];
        (void)b0;
    }
    {
        f32x4 f0 = ((const f32x4*)(bf_ + d0))[0], f1 = ((const f32x4*)(bf_ + d0))[1];
        f32x4 r0 = ((const f32x4*)(br_ + d0))[0], r1 = ((const f32x4*)(br_ + d0))[1];
#pragma unroll
        for (int j = 0; j < 4; ++j) { af[j] = f0[j]; af[4 + j] = f1[j];
                                      ar[j] = r0[j]; ar[4 + j] = r1[j]; }
    }
#pragma unroll
    for (int j7 = 0; j7 < 7; ++j7) {
        int tt = t + j7 - 3;
        if (tt >= 0 && tt < LL) {
            bf16x8 xv = *(const bf16x8*)&xp[(size_t)(b * LL + tt) * DI + d0];
            if (j7 < 4) {           // fwd k = j7
#pragma unroll
                for (int j = 0; j < 8; ++j) af[j] += wvf[j][j7] * (float)xv[j];
            }
            if (j7 >= 3) {          // rev k = 6 - j7
#pragma unroll
                for (int j = 0; j < 8; ++j) ar[j] += wvr[j][6 - j7] * (float)xv[j];
            }
        }
    }
    bf16x8 of, orv;
#pragma unroll
    for (int j = 0; j < 8; ++j) {
        of[j]  = (__bf16)(af[j] / (1.f + __expf(-af[j])));
        orv[j] = (__bf16)(ar[j] / (1.f + __expf(-ar[j])));
    }
    *(bf16x8*)&xf[row * DI + d0] = of;
    *(bf16x8*)&xr[row * DI + d0] = orv;
}

// Pass 1 (both dirs): per-chunk local scan from h=0, TWO d's per thread.
// blockIdx.z in 0..3: dir = z>>1, d-block = z&1.
__global__ __launch_bounds__(256) void scan_pass1_both(
    bf16h* dty_f, bf16h* dty_r,
    const bf16h* __restrict__ xc_f, const bf16h* __restrict__ xc_r,
    const bf16h* __restrict__ xdb_f, const bf16h* __restrict__ xdb_r,
    const float* __restrict__ At_f, const float* __restrict__ At_r,
    float* __restrict__ st_f, float* __restrict__ st_r,
    float* __restrict__ sd_f, float* __restrict__ sd_r,
    bf16h* __restrict__ cum_f, bf16h* __restrict__ cum_r)
{
    int c = blockIdx.x, b = blockIdx.y;
    int z = blockIdx.z, dir = z >> 1;
    int d0 = ((z & 1) * 256 + threadIdx.x) * 2;
    bf16h* dt_y = dir ? dty_r : dty_f;
    const bf16h* xcp = dir ? xc_r : xc_f;
    const bf16h* xdb = dir ? xdb_r : xdb_f;
    const float* Atab = dir ? At_r : At_f;
    float* state = dir ? st_r : st_f;
    float* sumdt = dir ? sd_r : sd_f;
    bf16h* cumdt = dir ? cum_r : cum_f;

    f32x2 Av[DS];
#pragma unroll
    for (int n = 0; n < DS; ++n) Av[n] = *(const f32x2*)&Atab[n * DI + d0];
    f32x2 h[DS];
#pragma unroll
    for (int n = 0; n < DS; ++n) h[n] = (f32x2){0.f, 0.f};
    f32x2 sdt = (f32x2){0.f, 0.f};
    for (int i = 0; i < LC; ++i) {
        int s = c * LC + i;
        int t = dir ? (LL - 1 - s) : s;
        size_t row = (size_t)(b * LL + t);
        size_t rowd = row * DI + d0;
        bf16x2 dt2 = *(const bf16x2*)&dt_y[rowd];
        bf16x2 xc2 = *(const bf16x2*)&xcp[rowd];
        f32x2 dtv = {(float)dt2[0], (float)dt2[1]};
        f32x2 dtx = {dtv[0] * (float)xc2[0], dtv[1] * (float)xc2[1]};
        const bf16h* bc = xdb + row * 64 + 32;   // B_t (row-uniform)
        const bf16h* cc = bc + 16;               // C_t
        sdt[0] += dtv[0]; sdt[1] += dtv[1];
        f32x2 y = (f32x2){0.f, 0.f};
#pragma unroll
        for (int n = 0; n < DS; ++n) {
            float bn = __bfloat162float(bc[n]);
            float cn = __bfloat162float(cc[n]);
            h[n][0] = EXP2F(dtv[0] * Av[n][0]) * h[n][0] + dtx[0] * bn;
            h[n][1] = EXP2F(dtv[1] * Av[n][1]) * h[n][1] + dtx[1] * bn;
            y[0] += h[n][0] * cn;
            y[1] += h[n][1] * cn;
        }
        bf16x2 cw2; cw2[0] = (__bf16)sdt[0]; cw2[1] = (__bf16)sdt[1];
        *(bf16x2*)&cumdt[rowd] = cw2;
        bf16x2 yw2; yw2[0] = (__bf16)y[0]; yw2[1] = (__bf16)y[1];
        *(bf16x2*)&dt_y[rowd] = yw2;             // y_part overwrites dt
    }
    size_t sb = ((size_t)c * BB + b) * DS;
#pragma unroll
    for (int n = 0; n < DS; ++n)
        *(f32x2*)&state[(sb + n) * DI + d0] = h[n];   // coalesced
    *(f32x2*)&sumdt[((size_t)c * BB + b) * DI + d0] = sdt;
}

// Pass 2 (both dirs): sequential prefix over chunks.
__global__ __launch_bounds__(256) void scan_pass2_both(
    const float* __restrict__ At_f, const float* __restrict__ At_r,
    const float* __restrict__ sd_f, const float* __restrict__ sd_r,
    float* __restrict__ st_f, float* __restrict__ st_r)
{
    int gid = blockIdx.x * 256 + threadIdx.x;   // over 2*BB*DS*DI
    int dir = gid >> 16;
    int rr = gid & 65535;
    int d = rr & (DI - 1), n = (rr >> 10) & (DS - 1), b = rr >> 14;
    const float* Atab = dir ? At_r : At_f;
    const float* sumdt = dir ? sd_r : sd_f;
    float* state = dir ? st_r : st_f;
    float Av = Atab[n * DI + d];
    float carry = 0.f;
    for (int c = 0; c < NC; ++c) {
        size_t si = (((size_t)c * BB + b) * DS + n) * DI + d;
        float hend = state[si];
        float dec  = EXP2F(Av * sumdt[((size_t)c * BB + b) * DI + d]);
        state[si] = carry;
        carry = carry * dec + hend;
    }
}

// Fixup (both dirs, fused): FOUR consecutive rows per thread at fixed d.
//   out = (y_f + y_r) * silu(z)   -- gate shared by both directions.
// Writes yb exactly once (no read-modify-write).
__global__ __launch_bounds__(256) void scan_fixup_both(
    const bf16h* __restrict__ yp_f, const bf16h* __restrict__ yp_r,
    const bf16h* __restrict__ cum_f, const bf16h* __restrict__ cum_r,
    const bf16h* __restrict__ xc_f, const bf16h* __restrict__ xc_r,
    const bf16h* __restrict__ zp,
    const bf16h* __restrict__ xdb_f, const bf16h* __restrict__ xdb_r,
    const float* __restrict__ At_f, const float* __restrict__ At_r,
    const float* __restrict__ Dp_f, const float* __restrict__ Dp_r,
    const float* __restrict__ st_f, const float* __restrict__ st_r,
    bf16h* __restrict__ yb)
{
    int g = blockIdx.x * 256 + threadIdx.x;     // over MR/4 * DI
    int d = g & (DI - 1);
    int rg = g >> 10;
    int t0 = (rg & (LL / 4 - 1)) * 4;
    int b = rg >> 9;
    int cf = t0 / LC;                            // fwd chunk
    int cr = (LL - 4 - t0) / LC;                 // rev chunk (4-aligned, same chunk)

    float Df = Dp_f[d], Dr = Dp_r[d];
    const float* hbf = st_f + ((size_t)cf * BB + b) * DS * DI + d;
    const float* hbr = st_r + ((size_t)cr * BB + b) * DS * DI + d;
    float Avf[DS], Avr[DS], hif[DS], hir[DS];
#pragma unroll
    for (int n = 0; n < DS; ++n) {
        Avf[n] = At_f[n * DI + d];
        Avr[n] = At_r[n * DI + d];
        hif[n] = hbf[(size_t)n * DI];
        hir[n] = hbr[(size_t)n * DI];
    }

#pragma unroll
    for (int r = 0; r < 4; ++r) {
        size_t row = (size_t)(b * LL + t0 + r);
        size_t idx = row * DI + d;
        const bf16h* ccf = xdb_f + row * 64 + 48;   // C_t fwd (row-uniform)
        const bf16h* ccr = xdb_r + row * 64 + 48;   // C_t rev
        float cumf = __bfloat162float(cum_f[idx]);
        float cumr = __bfloat162float(cum_r[idx]);
        float dyf = 0.f, dyr = 0.f;
#pragma unroll
        for (int n = 0; n < DS; ++n) {
            dyf += hif[n] * EXP2F(Avf[n] * cumf) * __bfloat162float(ccf[n]);
            dyr += hir[n] * EXP2F(Avr[n] * cumr) * __bfloat162float(ccr[n]);
        }
        float yf = __bfloat162float(yp_f[idx]) + dyf + Df * __bfloat162float(xc_f[idx]);
        float yr = __bfloat162float(yp_r[idx]) + dyr + Dr * __bfloat162float(xc_r[idx]);
        float zv = __bfloat162float(zp[idx]);
        float gate = zv / (1.f + __expf(-zv));
        yb[idx] = __float2bfloat16((yf + yr) * gate);
    }
}

extern "C" void kernel_launch(void* const* d_in, const int* in_sizes, int n_in,
                              void* d_out, int out_size, void* d_ws, size_t ws_size,
                              hipStream_t stream)
{
    const float* hidden = (const float*)d_in[0];
    const float* W_in   = (const float*)d_in[1];
    const float* W_out  = (const float*)d_in[2];
    const float* cw[2]  = {(const float*)d_in[3],  (const float*)d_in[10]};
    const float* cb[2]  = {(const float*)d_in[4],  (const float*)d_in[11]};
    const float* Wx[2]  = {(const float*)d_in[5],  (const float*)d_in[12]};
    const float* Wdt[2] = {(const float*)d_in[6],  (const float*)d_in[13]};
    const float* bdt[2] = {(const float*)d_in[7],  (const float*)d_in[14]};
    const float* Al[2]  = {(const float*)d_in[8],  (const float*)d_in[15]};
    const float* Dp[2]  = {(const float*)d_in[9],  (const float*)d_in[16]};

    // ---- workspace: ~208.7 MiB of the 256 MiB d_ws, no aliasing ----
    char* ws = (char*)d_ws;
    bf16h* hidden_b = (bf16h*)ws;  ws += (size_t)MR * DM * 2;            // 8 MiB
    bf16h* Win_b    = (bf16h*)ws;  ws += (size_t)2048 * 512 * 2;         // 2 MiB
    bf16h* Wx_b[2];  Wx_b[0]  = (bf16h*)ws; ws += (size_t)64 * DI * 2;   // .125
                     Wx_b[1]  = (bf16h*)ws; ws += (size_t)64 * DI * 2;
    bf16h* Wdt_b[2]; Wdt_b[0] = (bf16h*)ws; ws += (size_t)DI * 32 * 2;   // .0625
                     Wdt_b[1] = (bf16h*)ws; ws += (size_t)DI * 32 * 2;
    bf16h* Wout_b   = (bf16h*)ws;  ws += (size_t)DM * DI * 2;            // 1 MiB
    bf16h* bufX     = (bf16h*)ws;  ws += (size_t)MR * DI * 2;            // 16 MiB
    bf16h* bufZ     = (bf16h*)ws;  ws += (size_t)MR * DI * 2;            // 16 MiB
    bf16h* xcb[2];   xcb[0]   = (bf16h*)ws; ws += (size_t)MR * DI * 2;   // 16 x2
                     xcb[1]   = (bf16h*)ws; ws += (size_t)MR * DI * 2;
    bf16h* xdbl[2];  xdbl[0]  = (bf16h*)ws; ws += (size_t)MR * 64 * 2;   // 1 x2
                     xdbl[1]  = (bf16h*)ws; ws += (size_t)MR * 64 * 2;
    bf16h* dtb[2];   dtb[0]   = (bf16h*)ws; ws += (size_t)MR * DI * 2;   // 16 x2
                     dtb[1]   = (bf16h*)ws; ws += (size_t)MR * DI * 2;
    bf16h* cum[2];   cum[0]   = (bf16h*)ws; ws += (size_t)MR * DI * 2;   // 16 x2
                     cum[1]   = (bf16h*)ws; ws += (size_t)MR * DI * 2;
    float* state[2]; state[0] = (float*)ws; ws += (size_t)NC * BB * DS * DI * 4; // 16 x2
                     state[1] = (float*)ws; ws += (size_t)NC * BB * DS * DI * 4;
    float* sumdt[2]; sumdt[0] = (float*)ws; ws += (size_t)NC * BB * DI * 4;      // 1 x2
                     sumdt[1] = (float*)ws; ws += (size_t)NC * BB * DI * 4;
    bf16h* yb       = (bf16h*)ws;  ws += (size_t)MR * DI * 2;            // 16 MiB
    float* Atab[2];  Atab[0]  = (float*)ws; ws += (size_t)DS * DI * 4;   // 64K x2
                     Atab[1]  = (float*)ws; ws += (size_t)DS * DI * 4;

    dim3 blk(256);

    // 1. all f32 -> bf16 conversions in one launch
    cvt_all<<<dim3(5824), blk, 0, stream>>>(
        hidden, W_in, Wx[0], Wx[1], Wdt[0], Wdt[1], W_out,
        hidden_b, Win_b, Wx_b[0], Wx_b[1], Wdt_b[0], Wdt_b[1], Wout_b);

    // 2. A-tables, both dirs
    make_atab_both<<<dim3(2 * DS * DI / 256), blk, 0, stream>>>(
        Al[0], Al[1], Atab[0], Atab[1]);

    // 3. xz = hidden @ W_in^T; split X / Z planes
    gemm_nt<128, 128, 64, 2, 2, 2><<<dim3(16, 64, 1), blk, 0, stream>>>(
        (const __bf16*)hidden_b, (const __bf16*)Win_b, nullptr, nullptr,
        nullptr, bufX, bufZ, nullptr, nullptr, 512, 512, 512, 1024);

    // 4. conv + silu, both dirs in one pass over bufX
    conv_both<<<dim3(MR * DI / 8 / 256), blk, 0, stream>>>(
        bufX, cw[0], cb[0], cw[1], cb[1], xcb[0], xcb[1]);

    // 5. x_dbl = xc @ W_x^T  (N=64, K=1024), z selects dir -> 512 blocks
    gemm_nt<32, 64, 64, 2, 2, 0><<<dim3(1, MR / 32, 2), blk, 0, stream>>>(
        (const __bf16*)xcb[0], (const __bf16*)Wx_b[0],
        (const __bf16*)xcb[1], (const __bf16*)Wx_b[1],
        nullptr, xdbl[0], xdbl[1], nullptr, nullptr, DI, DI, DI, 64);

    // 6. dt = softplus(dt_r @ W_dt^T + b_dt)  (N=1024, K=32), z dir
    gemm_nt<128, 128, 32, 2, 2, 3><<<dim3(8, 64, 2), blk, 0, stream>>>(
        (const __bf16*)xdbl[0], (const __bf16*)Wdt_b[0],
        (const __bf16*)xdbl[1], (const __bf16*)Wdt_b[1],
        nullptr, dtb[0], dtb[1], bdt[0], bdt[1], 32, 64, 32, DI);

    // 7. chunk-local scans, both dirs (z = dir*2 + d-block)
    scan_pass1_both<<<dim3(NC, BB, 4), blk, 0, stream>>>(
        dtb[0], dtb[1], xcb[0], xcb[1], xdbl[0], xdbl[1],
        Atab[0], Atab[1], state[0], state[1], sumdt[0], sumdt[1],
        cum[0], cum[1]);

    // 8. chunk prefix, both dirs
    scan_pass2_both<<<dim3(2 * BB * DS * DI / 256), blk, 0, stream>>>(
        Atab[0], Atab[1], sumdt[0], sumdt[1], state[0], state[1]);

    // 9. fused fixup: out = (y_f + y_r) * silu(z), single yb write
    scan_fixup_both<<<dim3(MR / 4 * DI / 256), blk, 0, stream>>>(
        dtb[0], dtb[1], cum[0], cum[1], xcb[0], xcb[1], bufZ,
        xdbl[0], xdbl[1], Atab[0], Atab[1], Dp[0], Dp[1],
        state[0], state[1], yb);

    // 10. out = yb @ W_out^T  (M=8192, N=512, K=1024) -> f32 d_out
    gemm_nt<128, 128, 64, 2, 2, 1><<<dim3(4, 64, 1), blk, 0, stream>>>(
        (const __bf16*)yb, (const __bf16*)Wout_b, nullptr, nullptr,
        (float*)d_out, nullptr, nullptr, nullptr, nullptr, DI, DI, DI, DM);
}

// Round 12
// 356.525 us; speedup vs baseline: 1.3925x; 1.3925x over previous
//
#include <hip/hip_runtime.h>
#include <hip/hip_bf16.h>

// ---------------------------------------------------------------------------
// Bidirectional Mamba block on MI355X (gfx950).  R12.
// R11 = 496 us (regression from 456): fused gemm4 ran 172 us, latency-bound
// (MfmaUtil 0.2%, VALU 32%, HBM 3%). Root cause: R11's z-select signature
// dropped __restrict__ -> epilogue bias[col] loads serialized against stores
// (reload + vmcnt wait per element); plus log1pf = slow ocml call.
// R12: __restrict__ restored on ALL gemm pointers; epilogue j-outer with
// bias hoisted per column; softplus via __logf(1+__expf(v)) (hw v_log_f32).
// All R11 fusions kept (10 dispatches).  ws 208.7 MiB, no aliasing.
// ---------------------------------------------------------------------------

using bf16h = __hip_bfloat16;
typedef __bf16 bf16x8 __attribute__((ext_vector_type(8)));
typedef __bf16 bf16x4 __attribute__((ext_vector_type(4)));
typedef __bf16 bf16x2 __attribute__((ext_vector_type(2)));
typedef float f32x4 __attribute__((ext_vector_type(4)));
typedef float f32x2 __attribute__((ext_vector_type(2)));

#define BB 4
#define LL 2048
#define DM 512
#define DI 1024
#define DS 16
#define MR (BB * LL)   // 8192 rows
#define NC 64          // scan chunks
#define LC 32          // chunk length
#define LOG2E 1.44269504088896f

#if defined(__has_builtin)
#if __has_builtin(__builtin_amdgcn_exp2f)
#define EXP2F(x) __builtin_amdgcn_exp2f(x)
#else
#define EXP2F(x) exp2f(x)
#endif
#else
#define EXP2F(x) exp2f(x)
#endif

// async global->LDS, 16B per lane; LDS dest is wave-uniform base (+lane*16 by HW)
__device__ __forceinline__ void async_copy16(const void* g, void* l) {
    __builtin_amdgcn_global_load_lds(
        (const __attribute__((address_space(1))) unsigned int*)g,
        (__attribute__((address_space(3))) unsigned int*)l,
        16, 0, 0);
}

// One kernel converts all 7 f32 tensors to bf16 (4 elems/thread, 1024/block).
__global__ __launch_bounds__(256) void cvt_all(
    const float* __restrict__ s0, const float* __restrict__ s1,
    const float* __restrict__ s2, const float* __restrict__ s3,
    const float* __restrict__ s4, const float* __restrict__ s5,
    const float* __restrict__ s6,
    bf16h* __restrict__ d0, bf16h* __restrict__ d1, bf16h* __restrict__ d2,
    bf16h* __restrict__ d3, bf16h* __restrict__ d4, bf16h* __restrict__ d5,
    bf16h* __restrict__ d6)
{
    int blk = blockIdx.x;
    const float* src; bf16h* dst; int off;
    if      (blk < 4096) { src = s0; dst = d0; off = blk; }
    else if (blk < 5120) { src = s1; dst = d1; off = blk - 4096; }
    else if (blk < 5184) { src = s2; dst = d2; off = blk - 5120; }
    else if (blk < 5248) { src = s3; dst = d3; off = blk - 5184; }
    else if (blk < 5280) { src = s4; dst = d4; off = blk - 5248; }
    else if (blk < 5312) { src = s5; dst = d5; off = blk - 5280; }
    else                 { src = s6; dst = d6; off = blk - 5312; }
    int i = off * 256 + threadIdx.x;
    f32x4 v = ((const f32x4*)src)[i];
    bf16x4 o;
#pragma unroll
    for (int j = 0; j < 4; ++j) o[j] = (__bf16)v[j];
    ((bf16x4*)dst)[i] = o;
}

// Atab[n*DI + d] = -exp(Alog[d*DS + n]) * log2(e), both directions.
__global__ __launch_bounds__(256) void make_atab_both(
    const float* __restrict__ Al_f, const float* __restrict__ Al_r,
    float* __restrict__ At_f, float* __restrict__ At_r)
{
    int i = blockIdx.x * 256 + threadIdx.x;     // over 2*DS*DI
    int dir = i >> 14, j = i & (DS * DI - 1);
    int d = j & (DI - 1), n = j >> 10;
    const float* Al = dir ? Al_r : Al_f;
    float* At = dir ? At_r : At_f;
    At[j] = -__expf(Al[d * DS + n]) * LOG2E;
}

// NT GEMM: C[m][n] = sum_k A[m][k] * B[n][k]; A,B bf16 row-major.
// blockIdx.z selects pointer set for dual-direction launches.
// EPI: 0 = bf16 store O | 1 = f32 store OF1 |
//      2 = split: col<1024 -> O1, col>=1024 -> O2 (both ld 1024; z==0 only) |
//      3 = softplus(acc + bias[col]) -> bf16 O  (bias hoisted per column).
template <int BM, int BN, int BK, int WROWS, int WCOLS, int EPI>
__global__ __launch_bounds__(256) void gemm_nt(
    const __bf16* __restrict__ A1, const __bf16* __restrict__ B1,
    const __bf16* __restrict__ A2, const __bf16* __restrict__ B2,
    float* __restrict__ OF1, bf16h* __restrict__ O1, bf16h* __restrict__ O2,
    const float* __restrict__ bias1, const float* __restrict__ bias2,
    int K, int lda, int ldb, int ldc)
{
    constexpr int MT  = BM / (16 * WROWS);
    constexpr int NT_ = BN / (16 * WCOLS);
    constexpr int KCH = BK / 8;             // 16B chunks per row
    constexpr int ACH = BM * KCH / 256;
    constexpr int BCH = BN * KCH / 256;
    __shared__ alignas(16) __bf16 As[BM * BK];
    __shared__ alignas(16) __bf16 Bs[BN * BK];

    const __bf16* A = A1; const __bf16* B = B1;
    bf16h* OB = O1; const float* bias = bias1;
    if (blockIdx.z) { A = A2; B = B2; OB = O2; bias = bias2; }

    const int tid  = threadIdx.x, wave = tid >> 6, lane = tid & 63;
    const int quad = lane >> 4, l16 = lane & 15;
    const int wm = wave / WCOLS, wn = wave % WCOLS;
    const int bm0 = blockIdx.y * BM, bn0 = blockIdx.x * BN;

    f32x4 acc[MT][NT_];
#pragma unroll
    for (int i = 0; i < MT; ++i)
#pragma unroll
        for (int j = 0; j < NT_; ++j) acc[i][j] = (f32x4){0.f, 0.f, 0.f, 0.f};

    for (int k0 = 0; k0 < K; k0 += BK) {
#pragma unroll
        for (int i = 0; i < ACH; ++i) {
            int c = i * 256 + wave * 64 + lane;
            int r = c / KCH, cb = c % KCH;
            async_copy16(A + (size_t)(bm0 + r) * lda + k0 + cb * 8,
                         (void*)(As + (size_t)(i * 256 + wave * 64) * 8));
        }
#pragma unroll
        for (int i = 0; i < BCH; ++i) {
            int c = i * 256 + wave * 64 + lane;
            int r = c / KCH, cb = c % KCH;
            async_copy16(B + (size_t)(bn0 + r) * ldb + k0 + cb * 8,
                         (void*)(Bs + (size_t)(i * 256 + wave * 64) * 8));
        }
        __syncthreads();
#pragma unroll
        for (int kk = 0; kk < BK; kk += 32) {
            bf16x8 af[MT], bfv[NT_];
#pragma unroll
            for (int i = 0; i < MT; ++i)
                af[i] = *(const bf16x8*)&As[(wm * MT * 16 + i * 16 + l16) * BK + kk + quad * 8];
#pragma unroll
            for (int j = 0; j < NT_; ++j)
                bfv[j] = *(const bf16x8*)&Bs[(wn * NT_ * 16 + j * 16 + l16) * BK + kk + quad * 8];
#pragma unroll
            for (int i = 0; i < MT; ++i)
#pragma unroll
                for (int j = 0; j < NT_; ++j)
                    acc[i][j] = __builtin_amdgcn_mfma_f32_16x16x32_bf16(af[i], bfv[j], acc[i][j], 0, 0, 0);
        }
        __syncthreads();
    }

    // epilogue, j-outer: per-column values (bias) hoisted
#pragma unroll
    for (int j = 0; j < NT_; ++j) {
        int col = bn0 + wn * NT_ * 16 + j * 16 + l16;      // C/D: col = lane&15
        float bv = 0.f;
        if constexpr (EPI == 3) bv = bias[col];
#pragma unroll
        for (int i = 0; i < MT; ++i) {
            int row0 = bm0 + wm * MT * 16 + i * 16 + quad * 4;  // row = quad*4+reg
#pragma unroll
            for (int r = 0; r < 4; ++r) {
                float v = acc[i][j][r];
                int row = row0 + r;
                if constexpr (EPI == 0) {
                    OB[(size_t)row * ldc + col] = __float2bfloat16(v);
                } else if constexpr (EPI == 1) {
                    OF1[(size_t)row * ldc + col] = v;
                } else if constexpr (EPI == 2) {
                    if (col < 1024) O1[(size_t)row * 1024 + col] = __float2bfloat16(v);
                    else O2[(size_t)row * 1024 + (col - 1024)] = __float2bfloat16(v);
                } else {
                    v += bv;
                    float sp = (v > 15.f) ? v : __logf(1.f + __expf(v));
                    OB[(size_t)row * ldc + col] = __float2bfloat16(sp);
                }
            }
        }
    }
}

// Both-direction depthwise conv + silu, 8 d/thread; x loaded once.
__global__ __launch_bounds__(256) void conv_both(
    const bf16h* __restrict__ xp,
    const float* __restrict__ wf, const float* __restrict__ bf_,
    const float* __restrict__ wr, const float* __restrict__ br_,
    bf16h* __restrict__ xf, bf16h* __restrict__ xr)
{
    int idx = blockIdx.x * 256 + threadIdx.x;   // over MR*DI/8
    int d0 = (idx << 3) & (DI - 1);
    size_t row = (size_t)(idx >> 7);            // 128 threads per row
    int t = (int)(row & (LL - 1));
    int b = (int)(row >> 11);

    f32x4 wvf[8], wvr[8];
#pragma unroll
    for (int j = 0; j < 8; ++j) {
        wvf[j] = ((const f32x4*)(wf + (size_t)d0 * 4))[j];
        wvr[j] = ((const f32x4*)(wr + (size_t)d0 * 4))[j];
    }
    float af[8], ar[8];
    {
        f32x4 f0 = ((const f32x4*)(bf_ + d0))[0], f1 = ((const f32x4*)(bf_ + d0))[1];
        f32x4 r0 = ((const f32x4*)(br_ + d0))[0], r1 = ((const f32x4*)(br_ + d0))[1];
#pragma unroll
        for (int j = 0; j < 4; ++j) { af[j] = f0[j]; af[4 + j] = f1[j];
                                      ar[j] = r0[j]; ar[4 + j] = r1[j]; }
    }
#pragma unroll
    for (int j7 = 0; j7 < 7; ++j7) {
        int tt = t + j7 - 3;
        if (tt >= 0 && tt < LL) {
            bf16x8 xv = *(const bf16x8*)&xp[(size_t)(b * LL + tt) * DI + d0];
            if (j7 < 4) {           // fwd k = j7
#pragma unroll
                for (int j = 0; j < 8; ++j) af[j] += wvf[j][j7] * (float)xv[j];
            }
            if (j7 >= 3) {          // rev k = 6 - j7
#pragma unroll
                for (int j = 0; j < 8; ++j) ar[j] += wvr[j][6 - j7] * (float)xv[j];
            }
        }
    }
    bf16x8 of, orv;
#pragma unroll
    for (int j = 0; j < 8; ++j) {
        of[j]  = (__bf16)(af[j] / (1.f + __expf(-af[j])));
        orv[j] = (__bf16)(ar[j] / (1.f + __expf(-ar[j])));
    }
    *(bf16x8*)&xf[row * DI + d0] = of;
    *(bf16x8*)&xr[row * DI + d0] = orv;
}

// Pass 1 (both dirs): per-chunk local scan from h=0, TWO d's per thread.
// blockIdx.z in 0..3: dir = z>>1, d-block = z&1.
__global__ __launch_bounds__(256) void scan_pass1_both(
    bf16h* dty_f, bf16h* dty_r,
    const bf16h* __restrict__ xc_f, const bf16h* __restrict__ xc_r,
    const bf16h* __restrict__ xdb_f, const bf16h* __restrict__ xdb_r,
    const float* __restrict__ At_f, const float* __restrict__ At_r,
    float* __restrict__ st_f, float* __restrict__ st_r,
    float* __restrict__ sd_f, float* __restrict__ sd_r,
    bf16h* __restrict__ cum_f, bf16h* __restrict__ cum_r)
{
    int c = blockIdx.x, b = blockIdx.y;
    int z = blockIdx.z, dir = z >> 1;
    int d0 = ((z & 1) * 256 + threadIdx.x) * 2;
    bf16h* dt_y = dir ? dty_r : dty_f;
    const bf16h* xcp = dir ? xc_r : xc_f;
    const bf16h* xdb = dir ? xdb_r : xdb_f;
    const float* Atab = dir ? At_r : At_f;
    float* state = dir ? st_r : st_f;
    float* sumdt = dir ? sd_r : sd_f;
    bf16h* cumdt = dir ? cum_r : cum_f;

    f32x2 Av[DS];
#pragma unroll
    for (int n = 0; n < DS; ++n) Av[n] = *(const f32x2*)&Atab[n * DI + d0];
    f32x2 h[DS];
#pragma unroll
    for (int n = 0; n < DS; ++n) h[n] = (f32x2){0.f, 0.f};
    f32x2 sdt = (f32x2){0.f, 0.f};
    for (int i = 0; i < LC; ++i) {
        int s = c * LC + i;
        int t = dir ? (LL - 1 - s) : s;
        size_t row = (size_t)(b * LL + t);
        size_t rowd = row * DI + d0;
        bf16x2 dt2 = *(const bf16x2*)&dt_y[rowd];
        bf16x2 xc2 = *(const bf16x2*)&xcp[rowd];
        f32x2 dtv = {(float)dt2[0], (float)dt2[1]};
        f32x2 dtx = {dtv[0] * (float)xc2[0], dtv[1] * (float)xc2[1]};
        const bf16h* bc = xdb + row * 64 + 32;   // B_t (row-uniform)
        const bf16h* cc = bc + 16;               // C_t
        sdt[0] += dtv[0]; sdt[1] += dtv[1];
        f32x2 y = (f32x2){0.f, 0.f};
#pragma unroll
        for (int n = 0; n < DS; ++n) {
            float bn = __bfloat162float(bc[n]);
            float cn = __bfloat162float(cc[n]);
            h[n][0] = EXP2F(dtv[0] * Av[n][0]) * h[n][0] + dtx[0] * bn;
            h[n][1] = EXP2F(dtv[1] * Av[n][1]) * h[n][1] + dtx[1] * bn;
            y[0] += h[n][0] * cn;
            y[1] += h[n][1] * cn;
        }
        bf16x2 cw2; cw2[0] = (__bf16)sdt[0]; cw2[1] = (__bf16)sdt[1];
        *(bf16x2*)&cumdt[rowd] = cw2;
        bf16x2 yw2; yw2[0] = (__bf16)y[0]; yw2[1] = (__bf16)y[1];
        *(bf16x2*)&dt_y[rowd] = yw2;             // y_part overwrites dt
    }
    size_t sb = ((size_t)c * BB + b) * DS;
#pragma unroll
    for (int n = 0; n < DS; ++n)
        *(f32x2*)&state[(sb + n) * DI + d0] = h[n];   // coalesced
    *(f32x2*)&sumdt[((size_t)c * BB + b) * DI + d0] = sdt;
}

// Pass 2 (both dirs): sequential prefix over chunks.
__global__ __launch_bounds__(256) void scan_pass2_both(
    const float* __restrict__ At_f, const float* __restrict__ At_r,
    const float* __restrict__ sd_f, const float* __restrict__ sd_r,
    float* __restrict__ st_f, float* __restrict__ st_r)
{
    int gid = blockIdx.x * 256 + threadIdx.x;   // over 2*BB*DS*DI
    int dir = gid >> 16;
    int rr = gid & 65535;
    int d = rr & (DI - 1), n = (rr >> 10) & (DS - 1), b = rr >> 14;
    const float* Atab = dir ? At_r : At_f;
    const float* sumdt = dir ? sd_r : sd_f;
    float* state = dir ? st_r : st_f;
    float Av = Atab[n * DI + d];
    float carry = 0.f;
    for (int c = 0; c < NC; ++c) {
        size_t si = (((size_t)c * BB + b) * DS + n) * DI + d;
        float hend = state[si];
        float dec  = EXP2F(Av * sumdt[((size_t)c * BB + b) * DI + d]);
        state[si] = carry;
        carry = carry * dec + hend;
    }
}

// Fixup (both dirs, fused): FOUR consecutive rows per thread at fixed d.
//   out = (y_f + y_r) * silu(z); yb written once.
__global__ __launch_bounds__(256) void scan_fixup_both(
    const bf16h* __restrict__ yp_f, const bf16h* __restrict__ yp_r,
    const bf16h* __restrict__ cum_f, const bf16h* __restrict__ cum_r,
    const bf16h* __restrict__ xc_f, const bf16h* __restrict__ xc_r,
    const bf16h* __restrict__ zp,
    const bf16h* __restrict__ xdb_f, const bf16h* __restrict__ xdb_r,
    const float* __restrict__ At_f, const float* __restrict__ At_r,
    const float* __restrict__ Dp_f, const float* __restrict__ Dp_r,
    const float* __restrict__ st_f, const float* __restrict__ st_r,
    bf16h* __restrict__ yb)
{
    int g = blockIdx.x * 256 + threadIdx.x;     // over MR/4 * DI
    int d = g & (DI - 1);
    int rg = g >> 10;
    int t0 = (rg & (LL / 4 - 1)) * 4;
    int b = rg >> 9;
    int cf = t0 / LC;                            // fwd chunk
    int cr = (LL - 4 - t0) / LC;                 // rev chunk (4-aligned)

    float Df = Dp_f[d], Dr = Dp_r[d];
    const float* hbf = st_f + ((size_t)cf * BB + b) * DS * DI + d;
    const float* hbr = st_r + ((size_t)cr * BB + b) * DS * DI + d;
    float Avf[DS], Avr[DS], hif[DS], hir[DS];
#pragma unroll
    for (int n = 0; n < DS; ++n) {
        Avf[n] = At_f[n * DI + d];
        Avr[n] = At_r[n * DI + d];
        hif[n] = hbf[(size_t)n * DI];
        hir[n] = hbr[(size_t)n * DI];
    }

#pragma unroll
    for (int r = 0; r < 4; ++r) {
        size_t row = (size_t)(b * LL + t0 + r);
        size_t idx = row * DI + d;
        const bf16h* ccf = xdb_f + row * 64 + 48;   // C_t fwd (row-uniform)
        const bf16h* ccr = xdb_r + row * 64 + 48;   // C_t rev
        float cumf = __bfloat162float(cum_f[idx]);
        float cumr = __bfloat162float(cum_r[idx]);
        float dyf = 0.f, dyr = 0.f;
#pragma unroll
        for (int n = 0; n < DS; ++n) {
            dyf += hif[n] * EXP2F(Avf[n] * cumf) * __bfloat162float(ccf[n]);
            dyr += hir[n] * EXP2F(Avr[n] * cumr) * __bfloat162float(ccr[n]);
        }
        float yf = __bfloat162float(yp_f[idx]) + dyf + Df * __bfloat162float(xc_f[idx]);
        float yr = __bfloat162float(yp_r[idx]) + dyr + Dr * __bfloat162float(xc_r[idx]);
        float zv = __bfloat162float(zp[idx]);
        float gate = zv / (1.f + __expf(-zv));
        yb[idx] = __float2bfloat16((yf + yr) * gate);
    }
}

extern "C" void kernel_launch(void* const* d_in, const int* in_sizes, int n_in,
                              void* d_out, int out_size, void* d_ws, size_t ws_size,
                              hipStream_t stream)
{
    const float* hidden = (const float*)d_in[0];
    const float* W_in   = (const float*)d_in[1];
    const float* W_out  = (const float*)d_in[2];
    const float* cw[2]  = {(const float*)d_in[3],  (const float*)d_in[10]};
    const float* cb[2]  = {(const float*)d_in[4],  (const float*)d_in[11]};
    const float* Wx[2]  = {(const float*)d_in[5],  (const float*)d_in[12]};
    const float* Wdt[2] = {(const float*)d_in[6],  (const float*)d_in[13]};
    const float* bdt[2] = {(const float*)d_in[7],  (const float*)d_in[14]};
    const float* Al[2]  = {(const float*)d_in[8],  (const float*)d_in[15]};
    const float* Dp[2]  = {(const float*)d_in[9],  (const float*)d_in[16]};

    // ---- workspace: ~208.7 MiB of the 256 MiB d_ws, no aliasing ----
    char* ws = (char*)d_ws;
    bf16h* hidden_b = (bf16h*)ws;  ws += (size_t)MR * DM * 2;            // 8 MiB
    bf16h* Win_b    = (bf16h*)ws;  ws += (size_t)2048 * 512 * 2;         // 2 MiB
    bf16h* Wx_b[2];  Wx_b[0]  = (bf16h*)ws; ws += (size_t)64 * DI * 2;
                     Wx_b[1]  = (bf16h*)ws; ws += (size_t)64 * DI * 2;
    bf16h* Wdt_b[2]; Wdt_b[0] = (bf16h*)ws; ws += (size_t)DI * 32 * 2;
                     Wdt_b[1] = (bf16h*)ws; ws += (size_t)DI * 32 * 2;
    bf16h* Wout_b   = (bf16h*)ws;  ws += (size_t)DM * DI * 2;            // 1 MiB
    bf16h* bufX     = (bf16h*)ws;  ws += (size_t)MR * DI * 2;            // 16 MiB
    bf16h* bufZ     = (bf16h*)ws;  ws += (size_t)MR * DI * 2;            // 16 MiB
    bf16h* xcb[2];   xcb[0]   = (bf16h*)ws; ws += (size_t)MR * DI * 2;   // 16 x2
                     xcb[1]   = (bf16h*)ws; ws += (size_t)MR * DI * 2;
    bf16h* xdbl[2];  xdbl[0]  = (bf16h*)ws; ws += (size_t)MR * 64 * 2;   // 1 x2
                     xdbl[1]  = (bf16h*)ws; ws += (size_t)MR * 64 * 2;
    bf16h* dtb[2];   dtb[0]   = (bf16h*)ws; ws += (size_t)MR * DI * 2;   // 16 x2
                     dtb[1]   = (bf16h*)ws; ws += (size_t)MR * DI * 2;
    bf16h* cum[2];   cum[0]   = (bf16h*)ws; ws += (size_t)MR * DI * 2;   // 16 x2
                     cum[1]   = (bf16h*)ws; ws += (size_t)MR * DI * 2;
    float* state[2]; state[0] = (float*)ws; ws += (size_t)NC * BB * DS * DI * 4; // 16 x2
                     state[1] = (float*)ws; ws += (size_t)NC * BB * DS * DI * 4;
    float* sumdt[2]; sumdt[0] = (float*)ws; ws += (size_t)NC * BB * DI * 4;      // 1 x2
                     sumdt[1] = (float*)ws; ws += (size_t)NC * BB * DI * 4;
    bf16h* yb       = (bf16h*)ws;  ws += (size_t)MR * DI * 2;            // 16 MiB
    float* Atab[2];  Atab[0]  = (float*)ws; ws += (size_t)DS * DI * 4;
                     Atab[1]  = (float*)ws; ws += (size_t)DS * DI * 4;

    dim3 blk(256);

    // 1. all f32 -> bf16 conversions in one launch
    cvt_all<<<dim3(5824), blk, 0, stream>>>(
        hidden, W_in, Wx[0], Wx[1], Wdt[0], Wdt[1], W_out,
        hidden_b, Win_b, Wx_b[0], Wx_b[1], Wdt_b[0], Wdt_b[1], Wout_b);

    // 2. A-tables, both dirs
    make_atab_both<<<dim3(2 * DS * DI / 256), blk, 0, stream>>>(
        Al[0], Al[1], Atab[0], Atab[1]);

    // 3. xz = hidden @ W_in^T; split X / Z planes
    gemm_nt<128, 128, 64, 2, 2, 2><<<dim3(16, 64, 1), blk, 0, stream>>>(
        (const __bf16*)hidden_b, (const __bf16*)Win_b, nullptr, nullptr,
        nullptr, bufX, bufZ, nullptr, nullptr, 512, 512, 512, 1024);

    // 4. conv + silu, both dirs in one pass over bufX
    conv_both<<<dim3(MR * DI / 8 / 256), blk, 0, stream>>>(
        bufX, cw[0], cb[0], cw[1], cb[1], xcb[0], xcb[1]);

    // 5. x_dbl = xc @ W_x^T  (N=64, K=1024), z selects dir -> 512 blocks
    gemm_nt<32, 64, 64, 2, 2, 0><<<dim3(1, MR / 32, 2), blk, 0, stream>>>(
        (const __bf16*)xcb[0], (const __bf16*)Wx_b[0],
        (const __bf16*)xcb[1], (const __bf16*)Wx_b[1],
        nullptr, xdbl[0], xdbl[1], nullptr, nullptr, DI, DI, DI, 64);

    // 6. dt = softplus(dt_r @ W_dt^T + b_dt)  (N=1024, K=32), z dir
    gemm_nt<128, 128, 32, 2, 2, 3><<<dim3(8, 64, 2), blk, 0, stream>>>(
        (const __bf16*)xdbl[0], (const __bf16*)Wdt_b[0],
        (const __bf16*)xdbl[1], (const __bf16*)Wdt_b[1],
        nullptr, dtb[0], dtb[1], bdt[0], bdt[1], 32, 64, 32, DI);

    // 7. chunk-local scans, both dirs (z = dir*2 + d-block)
    scan_pass1_both<<<dim3(NC, BB, 4), blk, 0, stream>>>(
        dtb[0], dtb[1], xcb[0], xcb[1], xdbl[0], xdbl[1],
        Atab[0], Atab[1], state[0], state[1], sumdt[0], sumdt[1],
        cum[0], cum[1]);

    // 8. chunk prefix, both dirs
    scan_pass2_both<<<dim3(2 * BB * DS * DI / 256), blk, 0, stream>>>(
        Atab[0], Atab[1], sumdt[0], sumdt[1], state[0], state[1]);

    // 9. fused fixup: out = (y_f + y_r) * silu(z), single yb write
    scan_fixup_both<<<dim3(MR / 4 * DI / 256), blk, 0, stream>>>(
        dtb[0], dtb[1], cum[0], cum[1], xcb[0], xcb[1], bufZ,
        xdbl[0], xdbl[1], Atab[0], Atab[1], Dp[0], Dp[1],
        state[0], state[1], yb);

    // 10. out = yb @ W_out^T  (M=8192, N=512, K=1024) -> f32 d_out
    gemm_nt<128, 128, 64, 2, 2, 1><<<dim3(4, 64, 1), blk, 0, stream>>>(
        (const __bf16*)yb, (const __bf16*)Wout_b, nullptr, nullptr,
        (float*)d_out, nullptr, nullptr, nullptr, nullptr, DI, DI, DI, DM);
}

// Round 13
// 348.312 us; speedup vs baseline: 1.4254x; 1.0236x over previous
//
#include <hip/hip_runtime.h>
#include <hip/hip_bf16.h>

// ---------------------------------------------------------------------------
// Bidirectional Mamba block on MI355X (gfx950).  R13.
// R12 = 356 us. Leader: scan_pass1_both 65.6 us (Occ 28% — grid-starved at
// 1024 blocks; up to 32 scalar B/C loads per iter).
// R13:
//  - NC 64 -> 128 (LC=16): pass1 grid 2048 blocks (8/CU, 100% occ ceiling).
//  - B_t / C_t loaded as 2x bf16x8 each (dwordx4) in pass1 AND fixup.
//  - gemm2 tile 64x128: grid 256 -> 512 blocks (2/CU).
// ws 242.7 MiB <= 256 MiB, no aliasing.  10 dispatches unchanged otherwise.
// ---------------------------------------------------------------------------

using bf16h = __hip_bfloat16;
typedef __bf16 bf16x8 __attribute__((ext_vector_type(8)));
typedef __bf16 bf16x4 __attribute__((ext_vector_type(4)));
typedef __bf16 bf16x2 __attribute__((ext_vector_type(2)));
typedef float f32x4 __attribute__((ext_vector_type(4)));
typedef float f32x2 __attribute__((ext_vector_type(2)));

#define BB 4
#define LL 2048
#define DM 512
#define DI 1024
#define DS 16
#define MR (BB * LL)   // 8192 rows
#define NC 128         // scan chunks
#define LC 16          // chunk length
#define LOG2E 1.44269504088896f

#if defined(__has_builtin)
#if __has_builtin(__builtin_amdgcn_exp2f)
#define EXP2F(x) __builtin_amdgcn_exp2f(x)
#else
#define EXP2F(x) exp2f(x)
#endif
#else
#define EXP2F(x) exp2f(x)
#endif

// async global->LDS, 16B per lane; LDS dest is wave-uniform base (+lane*16 by HW)
__device__ __forceinline__ void async_copy16(const void* g, void* l) {
    __builtin_amdgcn_global_load_lds(
        (const __attribute__((address_space(1))) unsigned int*)g,
        (__attribute__((address_space(3))) unsigned int*)l,
        16, 0, 0);
}

// One kernel converts all 7 f32 tensors to bf16 (4 elems/thread, 1024/block).
__global__ __launch_bounds__(256) void cvt_all(
    const float* __restrict__ s0, const float* __restrict__ s1,
    const float* __restrict__ s2, const float* __restrict__ s3,
    const float* __restrict__ s4, const float* __restrict__ s5,
    const float* __restrict__ s6,
    bf16h* __restrict__ d0, bf16h* __restrict__ d1, bf16h* __restrict__ d2,
    bf16h* __restrict__ d3, bf16h* __restrict__ d4, bf16h* __restrict__ d5,
    bf16h* __restrict__ d6)
{
    int blk = blockIdx.x;
    const float* src; bf16h* dst; int off;
    if      (blk < 4096) { src = s0; dst = d0; off = blk; }
    else if (blk < 5120) { src = s1; dst = d1; off = blk - 4096; }
    else if (blk < 5184) { src = s2; dst = d2; off = blk - 5120; }
    else if (blk < 5248) { src = s3; dst = d3; off = blk - 5184; }
    else if (blk < 5280) { src = s4; dst = d4; off = blk - 5248; }
    else if (blk < 5312) { src = s5; dst = d5; off = blk - 5280; }
    else                 { src = s6; dst = d6; off = blk - 5312; }
    int i = off * 256 + threadIdx.x;
    f32x4 v = ((const f32x4*)src)[i];
    bf16x4 o;
#pragma unroll
    for (int j = 0; j < 4; ++j) o[j] = (__bf16)v[j];
    ((bf16x4*)dst)[i] = o;
}

// Atab[n*DI + d] = -exp(Alog[d*DS + n]) * log2(e), both directions.
__global__ __launch_bounds__(256) void make_atab_both(
    const float* __restrict__ Al_f, const float* __restrict__ Al_r,
    float* __restrict__ At_f, float* __restrict__ At_r)
{
    int i = blockIdx.x * 256 + threadIdx.x;     // over 2*DS*DI
    int dir = i >> 14, j = i & (DS * DI - 1);
    int d = j & (DI - 1), n = j >> 10;
    const float* Al = dir ? Al_r : Al_f;
    float* At = dir ? At_r : At_f;
    At[j] = -__expf(Al[d * DS + n]) * LOG2E;
}

// NT GEMM: C[m][n] = sum_k A[m][k] * B[n][k]; A,B bf16 row-major.
// blockIdx.z selects pointer set for dual-direction launches.
// EPI: 0 = bf16 store O | 1 = f32 store OF1 |
//      2 = split: col<1024 -> O1, col>=1024 -> O2 (both ld 1024; z==0 only) |
//      3 = softplus(acc + bias[col]) -> bf16 O  (bias hoisted per column).
template <int BM, int BN, int BK, int WROWS, int WCOLS, int EPI>
__global__ __launch_bounds__(256) void gemm_nt(
    const __bf16* __restrict__ A1, const __bf16* __restrict__ B1,
    const __bf16* __restrict__ A2, const __bf16* __restrict__ B2,
    float* __restrict__ OF1, bf16h* __restrict__ O1, bf16h* __restrict__ O2,
    const float* __restrict__ bias1, const float* __restrict__ bias2,
    int K, int lda, int ldb, int ldc)
{
    constexpr int MT  = BM / (16 * WROWS);
    constexpr int NT_ = BN / (16 * WCOLS);
    constexpr int KCH = BK / 8;             // 16B chunks per row
    constexpr int ACH = BM * KCH / 256;
    constexpr int BCH = BN * KCH / 256;
    __shared__ alignas(16) __bf16 As[BM * BK];
    __shared__ alignas(16) __bf16 Bs[BN * BK];

    const __bf16* A = A1; const __bf16* B = B1;
    bf16h* OB = O1; const float* bias = bias1;
    if (blockIdx.z) { A = A2; B = B2; OB = O2; bias = bias2; }

    const int tid  = threadIdx.x, wave = tid >> 6, lane = tid & 63;
    const int quad = lane >> 4, l16 = lane & 15;
    const int wm = wave / WCOLS, wn = wave % WCOLS;
    const int bm0 = blockIdx.y * BM, bn0 = blockIdx.x * BN;

    f32x4 acc[MT][NT_];
#pragma unroll
    for (int i = 0; i < MT; ++i)
#pragma unroll
        for (int j = 0; j < NT_; ++j) acc[i][j] = (f32x4){0.f, 0.f, 0.f, 0.f};

    for (int k0 = 0; k0 < K; k0 += BK) {
#pragma unroll
        for (int i = 0; i < ACH; ++i) {
            int c = i * 256 + wave * 64 + lane;
            int r = c / KCH, cb = c % KCH;
            async_copy16(A + (size_t)(bm0 + r) * lda + k0 + cb * 8,
                         (void*)(As + (size_t)(i * 256 + wave * 64) * 8));
        }
#pragma unroll
        for (int i = 0; i < BCH; ++i) {
            int c = i * 256 + wave * 64 + lane;
            int r = c / KCH, cb = c % KCH;
            async_copy16(B + (size_t)(bn0 + r) * ldb + k0 + cb * 8,
                         (void*)(Bs + (size_t)(i * 256 + wave * 64) * 8));
        }
        __syncthreads();
#pragma unroll
        for (int kk = 0; kk < BK; kk += 32) {
            bf16x8 af[MT], bfv[NT_];
#pragma unroll
            for (int i = 0; i < MT; ++i)
                af[i] = *(const bf16x8*)&As[(wm * MT * 16 + i * 16 + l16) * BK + kk + quad * 8];
#pragma unroll
            for (int j = 0; j < NT_; ++j)
                bfv[j] = *(const bf16x8*)&Bs[(wn * NT_ * 16 + j * 16 + l16) * BK + kk + quad * 8];
#pragma unroll
            for (int i = 0; i < MT; ++i)
#pragma unroll
                for (int j = 0; j < NT_; ++j)
                    acc[i][j] = __builtin_amdgcn_mfma_f32_16x16x32_bf16(af[i], bfv[j], acc[i][j], 0, 0, 0);
        }
        __syncthreads();
    }

    // epilogue, j-outer: per-column values (bias) hoisted
#pragma unroll
    for (int j = 0; j < NT_; ++j) {
        int col = bn0 + wn * NT_ * 16 + j * 16 + l16;      // C/D: col = lane&15
        float bv = 0.f;
        if constexpr (EPI == 3) bv = bias[col];
#pragma unroll
        for (int i = 0; i < MT; ++i) {
            int row0 = bm0 + wm * MT * 16 + i * 16 + quad * 4;  // row = quad*4+reg
#pragma unroll
            for (int r = 0; r < 4; ++r) {
                float v = acc[i][j][r];
                int row = row0 + r;
                if constexpr (EPI == 0) {
                    OB[(size_t)row * ldc + col] = __float2bfloat16(v);
                } else if constexpr (EPI == 1) {
                    OF1[(size_t)row * ldc + col] = v;
                } else if constexpr (EPI == 2) {
                    if (col < 1024) O1[(size_t)row * 1024 + col] = __float2bfloat16(v);
                    else O2[(size_t)row * 1024 + (col - 1024)] = __float2bfloat16(v);
                } else {
                    v += bv;
                    float sp = (v > 15.f) ? v : __logf(1.f + __expf(v));
                    OB[(size_t)row * ldc + col] = __float2bfloat16(sp);
                }
            }
        }
    }
}

// Both-direction depthwise conv + silu, 8 d/thread; x loaded once.
__global__ __launch_bounds__(256) void conv_both(
    const bf16h* __restrict__ xp,
    const float* __restrict__ wf, const float* __restrict__ bf_,
    const float* __restrict__ wr, const float* __restrict__ br_,
    bf16h* __restrict__ xf, bf16h* __restrict__ xr)
{
    int idx = blockIdx.x * 256 + threadIdx.x;   // over MR*DI/8
    int d0 = (idx << 3) & (DI - 1);
    size_t row = (size_t)(idx >> 7);            // 128 threads per row
    int t = (int)(row & (LL - 1));
    int b = (int)(row >> 11);

    f32x4 wvf[8], wvr[8];
#pragma unroll
    for (int j = 0; j < 8; ++j) {
        wvf[j] = ((const f32x4*)(wf + (size_t)d0 * 4))[j];
        wvr[j] = ((const f32x4*)(wr + (size_t)d0 * 4))[j];
    }
    float af[8], ar[8];
    {
        f32x4 f0 = ((const f32x4*)(bf_ + d0))[0], f1 = ((const f32x4*)(bf_ + d0))[1];
        f32x4 r0 = ((const f32x4*)(br_ + d0))[0], r1 = ((const f32x4*)(br_ + d0))[1];
#pragma unroll
        for (int j = 0; j < 4; ++j) { af[j] = f0[j]; af[4 + j] = f1[j];
                                      ar[j] = r0[j]; ar[4 + j] = r1[j]; }
    }
#pragma unroll
    for (int j7 = 0; j7 < 7; ++j7) {
        int tt = t + j7 - 3;
        if (tt >= 0 && tt < LL) {
            bf16x8 xv = *(const bf16x8*)&xp[(size_t)(b * LL + tt) * DI + d0];
            if (j7 < 4) {           // fwd k = j7
#pragma unroll
                for (int j = 0; j < 8; ++j) af[j] += wvf[j][j7] * (float)xv[j];
            }
            if (j7 >= 3) {          // rev k = 6 - j7
#pragma unroll
                for (int j = 0; j < 8; ++j) ar[j] += wvr[j][6 - j7] * (float)xv[j];
            }
        }
    }
    bf16x8 of, orv;
#pragma unroll
    for (int j = 0; j < 8; ++j) {
        of[j]  = (__bf16)(af[j] / (1.f + __expf(-af[j])));
        orv[j] = (__bf16)(ar[j] / (1.f + __expf(-ar[j])));
    }
    *(bf16x8*)&xf[row * DI + d0] = of;
    *(bf16x8*)&xr[row * DI + d0] = orv;
}

// Pass 1 (both dirs): per-chunk local scan from h=0, TWO d's per thread.
// B_t / C_t loaded as 2x bf16x8 each (dwordx4).  blockIdx.z: dir*2 + d-half.
__global__ __launch_bounds__(256) void scan_pass1_both(
    bf16h* dty_f, bf16h* dty_r,
    const bf16h* __restrict__ xc_f, const bf16h* __restrict__ xc_r,
    const bf16h* __restrict__ xdb_f, const bf16h* __restrict__ xdb_r,
    const float* __restrict__ At_f, const float* __restrict__ At_r,
    float* __restrict__ st_f, float* __restrict__ st_r,
    float* __restrict__ sd_f, float* __restrict__ sd_r,
    bf16h* __restrict__ cum_f, bf16h* __restrict__ cum_r)
{
    int c = blockIdx.x, b = blockIdx.y;
    int z = blockIdx.z, dir = z >> 1;
    int d0 = ((z & 1) * 256 + threadIdx.x) * 2;
    bf16h* dt_y = dir ? dty_r : dty_f;
    const bf16h* xcp = dir ? xc_r : xc_f;
    const bf16h* xdb = dir ? xdb_r : xdb_f;
    const float* Atab = dir ? At_r : At_f;
    float* state = dir ? st_r : st_f;
    float* sumdt = dir ? sd_r : sd_f;
    bf16h* cumdt = dir ? cum_r : cum_f;

    f32x2 Av[DS];
#pragma unroll
    for (int n = 0; n < DS; ++n) Av[n] = *(const f32x2*)&Atab[n * DI + d0];
    f32x2 h[DS];
#pragma unroll
    for (int n = 0; n < DS; ++n) h[n] = (f32x2){0.f, 0.f};
    f32x2 sdt = (f32x2){0.f, 0.f};
    for (int i = 0; i < LC; ++i) {
        int s = c * LC + i;
        int t = dir ? (LL - 1 - s) : s;
        size_t row = (size_t)(b * LL + t);
        size_t rowd = row * DI + d0;
        bf16x2 dt2 = *(const bf16x2*)&dt_y[rowd];
        bf16x2 xc2 = *(const bf16x2*)&xcp[rowd];
        f32x2 dtv = {(float)dt2[0], (float)dt2[1]};
        f32x2 dtx = {dtv[0] * (float)xc2[0], dtv[1] * (float)xc2[1]};
        const bf16h* base = xdb + row * 64;
        bf16x8 bv0 = *(const bf16x8*)(base + 32);   // B_t[0..7]
        bf16x8 bv1 = *(const bf16x8*)(base + 40);   // B_t[8..15]
        bf16x8 cv0 = *(const bf16x8*)(base + 48);   // C_t[0..7]
        bf16x8 cv1 = *(const bf16x8*)(base + 56);   // C_t[8..15]
        sdt[0] += dtv[0]; sdt[1] += dtv[1];
        f32x2 y = (f32x2){0.f, 0.f};
#pragma unroll
        for (int n = 0; n < DS; ++n) {
            float bn = (float)((n < 8) ? bv0[n & 7] : bv1[n & 7]);
            float cn = (float)((n < 8) ? cv0[n & 7] : cv1[n & 7]);
            h[n][0] = EXP2F(dtv[0] * Av[n][0]) * h[n][0] + dtx[0] * bn;
            h[n][1] = EXP2F(dtv[1] * Av[n][1]) * h[n][1] + dtx[1] * bn;
            y[0] += h[n][0] * cn;
            y[1] += h[n][1] * cn;
        }
        bf16x2 cw2; cw2[0] = (__bf16)sdt[0]; cw2[1] = (__bf16)sdt[1];
        *(bf16x2*)&cumdt[rowd] = cw2;
        bf16x2 yw2; yw2[0] = (__bf16)y[0]; yw2[1] = (__bf16)y[1];
        *(bf16x2*)&dt_y[rowd] = yw2;             // y_part overwrites dt
    }
    size_t sb = ((size_t)c * BB + b) * DS;
#pragma unroll
    for (int n = 0; n < DS; ++n)
        *(f32x2*)&state[(sb + n) * DI + d0] = h[n];   // coalesced
    *(f32x2*)&sumdt[((size_t)c * BB + b) * DI + d0] = sdt;
}

// Pass 2 (both dirs): sequential prefix over chunks.
__global__ __launch_bounds__(256) void scan_pass2_both(
    const float* __restrict__ At_f, const float* __restrict__ At_r,
    const float* __restrict__ sd_f, const float* __restrict__ sd_r,
    float* __restrict__ st_f, float* __restrict__ st_r)
{
    int gid = blockIdx.x * 256 + threadIdx.x;   // over 2*BB*DS*DI
    int dir = gid >> 16;
    int rr = gid & 65535;
    int d = rr & (DI - 1), n = (rr >> 10) & (DS - 1), b = rr >> 14;
    const float* Atab = dir ? At_r : At_f;
    const float* sumdt = dir ? sd_r : sd_f;
    float* state = dir ? st_r : st_f;
    float Av = Atab[n * DI + d];
    float carry = 0.f;
    for (int c = 0; c < NC; ++c) {
        size_t si = (((size_t)c * BB + b) * DS + n) * DI + d;
        float hend = state[si];
        float dec  = EXP2F(Av * sumdt[((size_t)c * BB + b) * DI + d]);
        state[si] = carry;
        carry = carry * dec + hend;
    }
}

// Fixup (both dirs, fused): FOUR consecutive rows per thread at fixed d.
//   out = (y_f + y_r) * silu(z); yb written once.  C_t via bf16x8 loads.
__global__ __launch_bounds__(256) void scan_fixup_both(
    const bf16h* __restrict__ yp_f, const bf16h* __restrict__ yp_r,
    const bf16h* __restrict__ cum_f, const bf16h* __restrict__ cum_r,
    const bf16h* __restrict__ xc_f, const bf16h* __restrict__ xc_r,
    const bf16h* __restrict__ zp,
    const bf16h* __restrict__ xdb_f, const bf16h* __restrict__ xdb_r,
    const float* __restrict__ At_f, const float* __restrict__ At_r,
    const float* __restrict__ Dp_f, const float* __restrict__ Dp_r,
    const float* __restrict__ st_f, const float* __restrict__ st_r,
    bf16h* __restrict__ yb)
{
    int g = blockIdx.x * 256 + threadIdx.x;     // over MR/4 * DI
    int d = g & (DI - 1);
    int rg = g >> 10;
    int t0 = (rg & (LL / 4 - 1)) * 4;
    int b = rg >> 9;
    int cf = t0 / LC;                            // fwd chunk
    int cr = (LL - 4 - t0) / LC;                 // rev chunk (4-aligned, 4|LC)

    float Df = Dp_f[d], Dr = Dp_r[d];
    const float* hbf = st_f + ((size_t)cf * BB + b) * DS * DI + d;
    const float* hbr = st_r + ((size_t)cr * BB + b) * DS * DI + d;
    float Avf[DS], Avr[DS], hif[DS], hir[DS];
#pragma unroll
    for (int n = 0; n < DS; ++n) {
        Avf[n] = At_f[n * DI + d];
        Avr[n] = At_r[n * DI + d];
        hif[n] = hbf[(size_t)n * DI];
        hir[n] = hbr[(size_t)n * DI];
    }

#pragma unroll
    for (int r = 0; r < 4; ++r) {
        size_t row = (size_t)(b * LL + t0 + r);
        size_t idx = row * DI + d;
        const bf16h* bf_ = xdb_f + row * 64;
        const bf16h* br_ = xdb_r + row * 64;
        bf16x8 cf0 = *(const bf16x8*)(bf_ + 48);
        bf16x8 cf1 = *(const bf16x8*)(bf_ + 56);
        bf16x8 cr0 = *(const bf16x8*)(br_ + 48);
        bf16x8 cr1 = *(const bf16x8*)(br_ + 56);
        float cumf = __bfloat162float(cum_f[idx]);
        float cumr = __bfloat162float(cum_r[idx]);
        float dyf = 0.f, dyr = 0.f;
#pragma unroll
        for (int n = 0; n < DS; ++n) {
            float cnf = (float)((n < 8) ? cf0[n & 7] : cf1[n & 7]);
            float cnr = (float)((n < 8) ? cr0[n & 7] : cr1[n & 7]);
            dyf += hif[n] * EXP2F(Avf[n] * cumf) * cnf;
            dyr += hir[n] * EXP2F(Avr[n] * cumr) * cnr;
        }
        float yf = __bfloat162float(yp_f[idx]) + dyf + Df * __bfloat162float(xc_f[idx]);
        float yr = __bfloat162float(yp_r[idx]) + dyr + Dr * __bfloat162float(xc_r[idx]);
        float zv = __bfloat162float(zp[idx]);
        float gate = zv / (1.f + __expf(-zv));
        yb[idx] = __float2bfloat16((yf + yr) * gate);
    }
}

extern "C" void kernel_launch(void* const* d_in, const int* in_sizes, int n_in,
                              void* d_out, int out_size, void* d_ws, size_t ws_size,
                              hipStream_t stream)
{
    const float* hidden = (const float*)d_in[0];
    const float* W_in   = (const float*)d_in[1];
    const float* W_out  = (const float*)d_in[2];
    const float* cw[2]  = {(const float*)d_in[3],  (const float*)d_in[10]};
    const float* cb[2]  = {(const float*)d_in[4],  (const float*)d_in[11]};
    const float* Wx[2]  = {(const float*)d_in[5],  (const float*)d_in[12]};
    const float* Wdt[2] = {(const float*)d_in[6],  (const float*)d_in[13]};
    const float* bdt[2] = {(const float*)d_in[7],  (const float*)d_in[14]};
    const float* Al[2]  = {(const float*)d_in[8],  (const float*)d_in[15]};
    const float* Dp[2]  = {(const float*)d_in[9],  (const float*)d_in[16]};

    // ---- workspace: ~242.7 MiB of the 256 MiB d_ws, no aliasing ----
    char* ws = (char*)d_ws;
    bf16h* hidden_b = (bf16h*)ws;  ws += (size_t)MR * DM * 2;            // 8 MiB
    bf16h* Win_b    = (bf16h*)ws;  ws += (size_t)2048 * 512 * 2;         // 2 MiB
    bf16h* Wx_b[2];  Wx_b[0]  = (bf16h*)ws; ws += (size_t)64 * DI * 2;
                     Wx_b[1]  = (bf16h*)ws; ws += (size_t)64 * DI * 2;
    bf16h* Wdt_b[2]; Wdt_b[0] = (bf16h*)ws; ws += (size_t)DI * 32 * 2;
                     Wdt_b[1] = (bf16h*)ws; ws += (size_t)DI * 32 * 2;
    bf16h* Wout_b   = (bf16h*)ws;  ws += (size_t)DM * DI * 2;            // 1 MiB
    bf16h* bufX     = (bf16h*)ws;  ws += (size_t)MR * DI * 2;            // 16 MiB
    bf16h* bufZ     = (bf16h*)ws;  ws += (size_t)MR * DI * 2;            // 16 MiB
    bf16h* xcb[2];   xcb[0]   = (bf16h*)ws; ws += (size_t)MR * DI * 2;   // 16 x2
                     xcb[1]   = (bf16h*)ws; ws += (size_t)MR * DI * 2;
    bf16h* xdbl[2];  xdbl[0]  = (bf16h*)ws; ws += (size_t)MR * 64 * 2;   // 1 x2
                     xdbl[1]  = (bf16h*)ws; ws += (size_t)MR * 64 * 2;
    bf16h* dtb[2];   dtb[0]   = (bf16h*)ws; ws += (size_t)MR * DI * 2;   // 16 x2
                     dtb[1]   = (bf16h*)ws; ws += (size_t)MR * DI * 2;
    bf16h* cum[2];   cum[0]   = (bf16h*)ws; ws += (size_t)MR * DI * 2;   // 16 x2
                     cum[1]   = (bf16h*)ws; ws += (size_t)MR * DI * 2;
    float* state[2]; state[0] = (float*)ws; ws += (size_t)NC * BB * DS * DI * 4; // 32 x2
                     state[1] = (float*)ws; ws += (size_t)NC * BB * DS * DI * 4;
    float* sumdt[2]; sumdt[0] = (float*)ws; ws += (size_t)NC * BB * DI * 4;      // 2 x2
                     sumdt[1] = (float*)ws; ws += (size_t)NC * BB * DI * 4;
    bf16h* yb       = (bf16h*)ws;  ws += (size_t)MR * DI * 2;            // 16 MiB
    float* Atab[2];  Atab[0]  = (float*)ws; ws += (size_t)DS * DI * 4;
                     Atab[1]  = (float*)ws; ws += (size_t)DS * DI * 4;

    dim3 blk(256);

    // 1. all f32 -> bf16 conversions in one launch
    cvt_all<<<dim3(5824), blk, 0, stream>>>(
        hidden, W_in, Wx[0], Wx[1], Wdt[0], Wdt[1], W_out,
        hidden_b, Win_b, Wx_b[0], Wx_b[1], Wdt_b[0], Wdt_b[1], Wout_b);

    // 2. A-tables, both dirs
    make_atab_both<<<dim3(2 * DS * DI / 256), blk, 0, stream>>>(
        Al[0], Al[1], Atab[0], Atab[1]);

    // 3. xz = hidden @ W_in^T; split X / Z planes
    gemm_nt<128, 128, 64, 2, 2, 2><<<dim3(16, 64, 1), blk, 0, stream>>>(
        (const __bf16*)hidden_b, (const __bf16*)Win_b, nullptr, nullptr,
        nullptr, bufX, bufZ, nullptr, nullptr, 512, 512, 512, 1024);

    // 4. conv + silu, both dirs in one pass over bufX
    conv_both<<<dim3(MR * DI / 8 / 256), blk, 0, stream>>>(
        bufX, cw[0], cb[0], cw[1], cb[1], xcb[0], xcb[1]);

    // 5. x_dbl = xc @ W_x^T  (N=64, K=1024), z selects dir -> 512 blocks
    gemm_nt<32, 64, 64, 2, 2, 0><<<dim3(1, MR / 32, 2), blk, 0, stream>>>(
        (const __bf16*)xcb[0], (const __bf16*)Wx_b[0],
        (const __bf16*)xcb[1], (const __bf16*)Wx_b[1],
        nullptr, xdbl[0], xdbl[1], nullptr, nullptr, DI, DI, DI, 64);

    // 6. dt = softplus(dt_r @ W_dt^T + b_dt)  (N=1024, K=32), z dir
    gemm_nt<128, 128, 32, 2, 2, 3><<<dim3(8, 64, 2), blk, 0, stream>>>(
        (const __bf16*)xdbl[0], (const __bf16*)Wdt_b[0],
        (const __bf16*)xdbl[1], (const __bf16*)Wdt_b[1],
        nullptr, dtb[0], dtb[1], bdt[0], bdt[1], 32, 64, 32, DI);

    // 7. chunk-local scans, both dirs (z = dir*2 + d-half); 2048 blocks
    scan_pass1_both<<<dim3(NC, BB, 4), blk, 0, stream>>>(
        dtb[0], dtb[1], xcb[0], xcb[1], xdbl[0], xdbl[1],
        Atab[0], Atab[1], state[0], state[1], sumdt[0], sumdt[1],
        cum[0], cum[1]);

    // 8. chunk prefix, both dirs
    scan_pass2_both<<<dim3(2 * BB * DS * DI / 256), blk, 0, stream>>>(
        Atab[0], Atab[1], sumdt[0], sumdt[1], state[0], state[1]);

    // 9. fused fixup: out = (y_f + y_r) * silu(z), single yb write
    scan_fixup_both<<<dim3(MR / 4 * DI / 256), blk, 0, stream>>>(
        dtb[0], dtb[1], cum[0], cum[1], xcb[0], xcb[1], bufZ,
        xdbl[0], xdbl[1], Atab[0], Atab[1], Dp[0], Dp[1],
        state[0], state[1], yb);

    // 10. out = yb @ W_out^T  (M=8192, N=512, K=1024) -> f32 d_out; 512 blocks
    gemm_nt<64, 128, 64, 2, 2, 1><<<dim3(4, 128, 1), blk, 0, stream>>>(
        (const __bf16*)yb, (const __bf16*)Wout_b, nullptr, nullptr,
        (float*)d_out, nullptr, nullptr, nullptr, nullptr, DI, DI, DI, DM);
}